// Round 13
// baseline (1302.950 us; speedup 1.0000x reference)
//
#include <hip/hip_runtime.h>
#include <hip/hip_bf16.h>
#include <cstdint>
#include <cstddef>

typedef __attribute__((ext_vector_type(8))) __bf16 bf16x8;
typedef __attribute__((ext_vector_type(4))) float f32x4;
typedef __attribute__((ext_vector_type(4))) unsigned short us4;

#define GLOAD_LDS16(g, l)                                                        \
    __builtin_amdgcn_global_load_lds(                                            \
        (const __attribute__((address_space(1))) void*)(g),                      \
        (__attribute__((address_space(3))) void*)(l), 16, 0, 0)

static __device__ __forceinline__ unsigned short f2bf(float x) {
    unsigned int u = __builtin_bit_cast(unsigned int, x);
    return (unsigned short)((u + 0x7FFFu + ((u >> 16) & 1u)) >> 16);
}

// gelu(x) = x * sigmoid(1.5957691x + 0.0713548x^3)  (== tanh-form gelu)
static __device__ __forceinline__ float gelu_fast(float x) {
    const float p = x * x;
    const float u = x * fmaf(0.0713548162726f, p, 1.59576912161f);
    const float t = __expf(-u);
    return x * __builtin_amdgcn_rcpf(1.0f + t);
}

// ---------------- Router: logits -> softmax -> mask, plus h -> bf16 ----------
__global__ __launch_bounds__(256) void moe_router_kernel(
    const float* __restrict__ h, const float* __restrict__ Wr,
    const float* __restrict__ br, unsigned short* __restrict__ hbf,
    float* __restrict__ mw)
{
    const int lane = threadIdx.x & 63, wave = threadIdx.x >> 6;
    const int n = blockIdx.x * 4 + wave;  // one token per wave
    const float* hr = h + (size_t)n * 1024;
    const int base = lane * 16;

    float xs[16];
#pragma unroll
    for (int q = 0; q < 4; ++q) {
        f32x4 v = *(const f32x4*)(hr + base + q * 4);
        xs[q * 4 + 0] = v[0]; xs[q * 4 + 1] = v[1];
        xs[q * 4 + 2] = v[2]; xs[q * 4 + 3] = v[3];
    }
    float acc[8] = {0.f, 0.f, 0.f, 0.f, 0.f, 0.f, 0.f, 0.f};
#pragma unroll
    for (int j = 0; j < 16; ++j) {
        const float x = xs[j];
        const f32x4 w0 = *(const f32x4*)(Wr + (size_t)(base + j) * 8);
        const f32x4 w1 = *(const f32x4*)(Wr + (size_t)(base + j) * 8 + 4);
        acc[0] += x * w0[0]; acc[1] += x * w0[1]; acc[2] += x * w0[2]; acc[3] += x * w0[3];
        acc[4] += x * w1[0]; acc[5] += x * w1[1]; acc[6] += x * w1[2]; acc[7] += x * w1[3];
    }
#pragma unroll
    for (int q = 0; q < 4; ++q) {
        us4 o;
        o[0] = f2bf(xs[q * 4 + 0]); o[1] = f2bf(xs[q * 4 + 1]);
        o[2] = f2bf(xs[q * 4 + 2]); o[3] = f2bf(xs[q * 4 + 3]);
        *(us4*)(hbf + (size_t)n * 1024 + base + q * 4) = o;
    }
#pragma unroll
    for (int m = 32; m >= 1; m >>= 1)
#pragma unroll
        for (int e = 0; e < 8; ++e) acc[e] += __shfl_xor(acc[e], m, 64);

    if (lane == 0) {
        float l[8]; float mx = -1e30f;
#pragma unroll
        for (int e = 0; e < 8; ++e) { l[e] = acc[e] + br[e]; mx = fmaxf(mx, l[e]); }
        float s = 0.f;
#pragma unroll
        for (int e = 0; e < 8; ++e) { l[e] = __expf(l[e] - mx); s += l[e]; }
        const float inv = 1.0f / s;
#pragma unroll
        for (int e = 0; e < 8; ++e) {
            const float w = l[e] * inv;
            mw[(size_t)n * 8 + e] = (w > 0.05f) ? w : 0.0f;
        }
    }
}

// ----- Deterministic sorted compaction: count -> scan -> place ---------------
__global__ __launch_bounds__(256) void moe_cnt_kernel(
    const float* __restrict__ mw, int* __restrict__ blkcnt)   // [8][32]
{
    const int blk = blockIdx.x;
    const int n = blk * 256 + threadIdx.x;
    const int lane = threadIdx.x & 63, wv = threadIdx.x >> 6;
    __shared__ int wcnt[8][4];
#pragma unroll
    for (int e = 0; e < 8; ++e) {
        const unsigned long long m = __ballot(mw[(size_t)n * 8 + e] > 0.f);
        if (lane == 0) wcnt[e][wv] = __popcll(m);
    }
    __syncthreads();
    if (threadIdx.x < 8)
        blkcnt[threadIdx.x * 32 + blk] =
            wcnt[threadIdx.x][0] + wcnt[threadIdx.x][1] +
            wcnt[threadIdx.x][2] + wcnt[threadIdx.x][3];
}

__global__ __launch_bounds__(64) void moe_scan_kernel(
    const int* __restrict__ blkcnt, int* __restrict__ blkbase, int* __restrict__ cnt)
{
    const int e = threadIdx.x;
    if (e < 8) {
        int s = 0;
        for (int b = 0; b < 32; ++b) {
            blkbase[e * 32 + b] = s;
            s += blkcnt[e * 32 + b];
        }
        cnt[e] = s;
    }
}

__global__ __launch_bounds__(256) void moe_place_kernel(
    const float* __restrict__ mw, const int* __restrict__ blkbase,
    int* __restrict__ toklist)
{
    const int blk = blockIdx.x;
    const int n = blk * 256 + threadIdx.x;
    const int lane = threadIdx.x & 63, wv = threadIdx.x >> 6;
    __shared__ int wbase[8][4];
    unsigned long long msk[8];
#pragma unroll
    for (int e = 0; e < 8; ++e) {
        msk[e] = __ballot(mw[(size_t)n * 8 + e] > 0.f);
        if (lane == 0) wbase[e][wv] = __popcll(msk[e]);
    }
    __syncthreads();
    if (threadIdx.x < 8) {
        int s = blkbase[threadIdx.x * 32 + blk];
#pragma unroll
        for (int w = 0; w < 4; ++w) {
            const int c = wbase[threadIdx.x][w];
            wbase[threadIdx.x][w] = s;
            s += c;
        }
    }
    __syncthreads();
#pragma unroll
    for (int e = 0; e < 8; ++e) {
        if (msk[e] & (1ull << lane)) {
            const int pre = __popcll(msk[e] & ((1ull << lane) - 1ull));
            toklist[e * 8192 + wbase[e][wv] + pre] = n;
        }
    }
}

// -------- Zero-fill inactive ghid rows (once; inactive set fixed per call) ---
__global__ __launch_bounds__(256) void moe_zfill_kernel(
    const float* __restrict__ mw, unsigned short* __restrict__ ghid,
    int Fc, int ldAp)
{
    const int n = blockIdx.x, t = threadIdx.x;
    __shared__ float w[8];
    if (t < 8) w[t] = mw[(size_t)n * 8 + t];
    __syncthreads();
    const us4 z = {0, 0, 0, 0};
#pragma unroll
    for (int e = 0; e < 8; ++e) {
        if (w[e] == 0.f) {
            unsigned short* row = ghid + (size_t)n * ldAp + e * Fc;
            for (int c = t * 4; c < Fc; c += 1024)
                *(us4*)(row + c) = z;
        }
    }
}

// ---------- Transpose + fp32->bf16 convert (32x32 tiles, per expert z) -------
__global__ __launch_bounds__(256) void moe_tcvt_kernel(
    const float* __restrict__ in, unsigned short* __restrict__ out,
    int ls, size_t in_es, int os, size_t out_es)
{
    __shared__ unsigned short t[32][33];
    const int e = blockIdx.z;
    const int r = threadIdx.x >> 3, c = (threadIdx.x & 7) * 4;
    const float* I = in + (size_t)e * in_es + (size_t)(blockIdx.x * 32 + r) * ls + blockIdx.y * 32 + c;
    f32x4 v = *(const f32x4*)I;
    t[r][c + 0] = f2bf(v[0]); t[r][c + 1] = f2bf(v[1]);
    t[r][c + 2] = f2bf(v[2]); t[r][c + 3] = f2bf(v[3]);
    __syncthreads();
    unsigned short* O = out + (size_t)e * out_es + (size_t)(blockIdx.y * 32 + r) * os + blockIdx.x * 32 + c;
    us4 o;
    o[0] = t[c + 0][r]; o[1] = t[c + 1][r]; o[2] = t[c + 2][r]; o[3] = t[c + 3][r];
    *(us4*)O = o;
}

// ============ 8-phase 256x256 GEMM, BK=64, look-ahead ds_read pipeline =======
// MODE 0 (sorted token-compacted): block covers 256 positions of expert e0's
//   ASCENDING active token list; A rows gathered via toklist; tiles beyond
//   M_e early-exit.  ghid = mw * gelu(hbf @ W1t^T + b1)
// MODE 1: part[z] (+)= ghid[:, klo:klo+kspan] @ W2t^T   (fp32 RMW, dense)
#define MFMA_QUAD(MB, NB, AF, BQ)                                              \
  _Pragma("unroll") for (int mi_ = 0; mi_ < 4; ++mi_)                          \
  _Pragma("unroll") for (int ni_ = 0; ni_ < 2; ++ni_) {                        \
      acc[(MB)+mi_][(NB)+ni_] = __builtin_amdgcn_mfma_f32_16x16x32_bf16(       \
          BQ[ni_][1], AF[mi_][1], __builtin_amdgcn_mfma_f32_16x16x32_bf16(     \
          BQ[ni_][0], AF[mi_][0], acc[(MB)+mi_][(NB)+ni_], 0, 0, 0), 0, 0, 0); \
  }

#define BARX()   __builtin_amdgcn_s_barrier()
#define SBX()    __builtin_amdgcn_sched_barrier(0)
#define LGKM(N)  asm volatile("s_waitcnt lgkmcnt(" #N ")" ::: "memory")
#define VMC(N)   asm volatile("s_waitcnt vmcnt(" #N ")" ::: "memory")
#define PRIO1()  __builtin_amdgcn_s_setprio(1)
#define PRIO0()  __builtin_amdgcn_s_setprio(0)

template <int MODE>
__global__ __launch_bounds__(512) void moe_gemm8p(
    const unsigned short* __restrict__ A, int ldga,
    const unsigned short* __restrict__ Bbase, size_t estride, int ldb,
    const float* __restrict__ b1, const float* __restrict__ mw,
    unsigned short* __restrict__ Cg, int ldc,
    float* __restrict__ part,
    const int* __restrict__ cnt, const int* __restrict__ toklist,
    int logFc, int f0glob, int kspan, int init)
{
    __shared__ unsigned short sh[65536];   // 128 KiB: XA,XB,YA,YB (32KB each)
    char* sm = (char*)sh;
    const int XA = 0, XB = 32768, YA = 65536, YB = 98304;

    const int tid = threadIdx.x, lane = tid & 63, wv = tid >> 6;
    const int wr = wv >> 2, wc = wv & 3;

    // XCD-affine bijective block mapping (flat id % 8 == XCD).
    int bx, by;
    if constexpr (MODE == 0) {
        const int orig = blockIdx.x + blockIdx.y * 32;  // [0, 32*gy)
        const int c8 = orig & 7, j = orig >> 3;
        bx = c8 * 4 + (j & 3); by = j >> 2;
    } else {
        const int orig = blockIdx.x + blockIdx.y * 32;  // [0,128)
        const int c8 = orig & 7, j = orig >> 3;         // [0,16)
        bx = c8 * 4 + (j >> 2); by = j & 3;
    }
    const int m0 = bx * 256;
    const int n0 = by * 256;

    const int z = (MODE == 1) ? blockIdx.z : 0;
    const int klo = z * kspan;
    float* Cacc = (MODE == 1) ? part + (size_t)z * (8192 * 1024) : nullptr;

    // MODE0 fixed expert / B base
    int e0 = 0, fb = 0;
    const unsigned short* gB0 = nullptr;
    const int rl0 = tid >> 3;                          // row [0,64)
    const int gs8 = ((tid & 7) ^ (rl0 & 7)) * 8;       // XOR-swizzled src col
    const int l15 = lane & 15, l4 = lane >> 4, l7 = lane & 7;

    int Me = 0;
    int idxS[4], idxE[8];
    if constexpr (MODE == 0) {
        e0 = n0 >> logFc; fb = n0 - (e0 << logFc);
        gB0 = Bbase + (size_t)e0 * estride + (size_t)(fb + rl0) * ldb + gs8;
        Me = cnt[e0];
        if (m0 >= Me) return;                  // uniform early-exit
        const int* tl = toklist + e0 * 8192;
#pragma unroll
        for (int q = 0; q < 4; ++q) {
            int pos = m0 + rl0 + q * 64; if (pos > Me - 1) pos = Me - 1;
            idxS[q] = tl[pos];
        }
#pragma unroll
        for (int i = 0; i < 8; ++i) {
            int pos = m0 + wr * 128 + i * 16 + l15; if (pos > Me - 1) pos = Me - 1;
            idxE[i] = tl[pos];
        }
        VMC(0); SBX();                         // keep vmcnt ledger clean
    }
    const unsigned short* gA0 = A + (size_t)(m0 + rl0) * ldga + gs8;
    const int dstw = wv * 1024;

    auto stageA = [&](int reg, int kk, int q) {
        const unsigned short* ga;
        if constexpr (MODE == 0) {
            ga = A + (size_t)idxS[q] * ldga + gs8 + kk;
        } else {
            ga = gA0 + kk + (size_t)(q * 64) * ldga;
        }
        GLOAD_LDS16(ga, sm + reg + (q >> 1) * 16384 + (q & 1) * 8192 + dstw);
    };
    auto stageB = [&](int reg, int kk, int q) {
        const unsigned short* gb;
        if constexpr (MODE == 0) {
            gb = gB0 + kk;
        } else {
            const int e = kk >> logFc, kc = kk - (e << logFc);
            gb = Bbase + (size_t)e * estride + (size_t)(n0 + rl0) * ldb + kc + gs8;
        }
        GLOAD_LDS16(gb + (size_t)(q * 64) * ldb,
                    sm + reg + (q >> 1) * 16384 + (q & 1) * 8192 + dstw);
    };

    // ds_read swizzled addresses
    const int sA0 = (wr * 128 + l15) * 128 + (((0 + l4) ^ l7) << 4);
    const int sA1 = (wr * 128 + l15) * 128 + (((4 + l4) ^ l7) << 4);
    const int sB0 = (wc * 64 + l15) * 128 + (((0 + l4) ^ l7) << 4);
    const int sB1 = (wc * 64 + l15) * 128 + (((4 + l4) ^ l7) << 4);

    f32x4 acc[8][4] = {};
    bf16x8 afL[4][2], afH[4][2], bqL[2][2], bqH[2][2];

#define RD_AFL(BASE) _Pragma("unroll") for (int mi_=0;mi_<4;++mi_){            \
      afL[mi_][0] = *(const bf16x8*)(sm + (BASE) + sA0 + mi_*2048);            \
      afL[mi_][1] = *(const bf16x8*)(sm + (BASE) + sA1 + mi_*2048); }
#define RD_AFH(BASE) _Pragma("unroll") for (int mi_=0;mi_<4;++mi_){            \
      afH[mi_][0] = *(const bf16x8*)(sm + (BASE) + sA0 + (4+mi_)*2048);        \
      afH[mi_][1] = *(const bf16x8*)(sm + (BASE) + sA1 + (4+mi_)*2048); }
#define RD_BQL(BASE) _Pragma("unroll") for (int ni_=0;ni_<2;++ni_){            \
      bqL[ni_][0] = *(const bf16x8*)(sm + (BASE) + sB0 + ni_*2048);            \
      bqL[ni_][1] = *(const bf16x8*)(sm + (BASE) + sB1 + ni_*2048); }
#define RD_BQH(BASE) _Pragma("unroll") for (int ni_=0;ni_<2;++ni_){            \
      bqH[ni_][0] = *(const bf16x8*)(sm + (BASE) + sB0 + (2+ni_)*2048);        \
      bqH[ni_][1] = *(const bf16x8*)(sm + (BASE) + sB1 + (2+ni_)*2048); }

    const int niter = kspan >> 7;  // 2 K-tiles (2x64) per iteration

    // Prologue: stage X(t0), Y(t1); drain X; read X Q1 frags after barrier.
#pragma unroll
    for (int q = 0; q < 4; ++q) { stageA(XA, klo, q); stageB(XB, klo, q); }
#pragma unroll
    for (int q = 0; q < 4; ++q) { stageA(YA, klo + 64, q); stageB(YB, klo + 64, q); }
    VMC(8); SBX();
    BARX();
    RD_AFL(XA); RD_BQL(XB);

    for (int it = 0; it < niter; ++it) {
        const int kX2 = klo + it * 128 + 128;  // next X tile
        const int kY2 = klo + it * 128 + 192;  // next Y tile
        const bool g = (it + 1 < niter);
        // ---- P1: MFMA Q1(X); read-ahead bqH(X)
        RD_BQH(XB);
        BARX(); LGKM(4); SBX(); PRIO1(); MFMA_QUAD(0, 0, afL, bqL); PRIO0(); BARX();
        // ---- P2: MFMA Q2(X); read-ahead afH(X); stage nextX A q0,q2
        RD_AFH(XA);
        if (g) { stageA(XA, kX2, 0); stageA(XA, kX2, 2); }
        BARX(); LGKM(8); SBX(); PRIO1(); MFMA_QUAD(0, 2, afL, bqH); PRIO0(); BARX();
        // ---- P3: MFMA Q3(X); stage nextX B q0,q1
        if (g) { stageB(XB, kX2, 0); stageB(XB, kX2, 1); }
        BARX(); LGKM(0); SBX(); PRIO1(); MFMA_QUAD(4, 0, afH, bqL); PRIO0(); BARX();
        // ---- P4: stage nextX rest; vmcnt; barrier; read Y Q1; MFMA Q4(X)
        if (g) { stageA(XA, kX2, 1); stageA(XA, kX2, 3);
                 stageB(XB, kX2, 2); stageB(XB, kX2, 3);
                 VMC(8); } else { VMC(0); }
        SBX();
        BARX();
        RD_AFL(YA); RD_BQL(YB);
        SBX(); PRIO1(); MFMA_QUAD(4, 2, afH, bqH); PRIO0(); BARX();
        // ---- P5: MFMA Q1(Y); read-ahead bqH(Y)
        RD_BQH(YB);
        BARX(); LGKM(4); SBX(); PRIO1(); MFMA_QUAD(0, 0, afL, bqL); PRIO0(); BARX();
        // ---- P6: MFMA Q2(Y); read-ahead afH(Y); stage nextY A q0,q2
        RD_AFH(YA);
        if (g) { stageA(YA, kY2, 0); stageA(YA, kY2, 2); }
        BARX(); LGKM(8); SBX(); PRIO1(); MFMA_QUAD(0, 2, afL, bqH); PRIO0(); BARX();
        // ---- P7: MFMA Q3(Y); stage nextY B q0,q1
        if (g) { stageB(YB, kY2, 0); stageB(YB, kY2, 1); }
        BARX(); LGKM(0); SBX(); PRIO1(); MFMA_QUAD(4, 0, afH, bqL); PRIO0(); BARX();
        // ---- P8: stage nextY rest; vmcnt; barrier; read nextX Q1; MFMA Q4(Y)
        if (g) { stageA(YA, kY2, 1); stageA(YA, kY2, 3);
                 stageB(YB, kY2, 2); stageB(YB, kY2, 3);
                 VMC(8); } else { VMC(0); }
        SBX();
        BARX();
        if (g) { RD_AFL(XA); RD_BQL(XB); }
        SBX(); PRIO1(); MFMA_QUAD(4, 2, afH, bqH); PRIO0(); BARX();
    }

    // Epilogue
    const int nr0v = l4 * 4;
    if constexpr (MODE == 0) {
        const float* b1p = b1 + (size_t)e0 * 4096 + f0glob + fb;
        f32x4 b1v[4];
#pragma unroll
        for (int j = 0; j < 4; ++j)
            b1v[j] = *(const f32x4*)(b1p + wc * 64 + j * 16 + nr0v);
#pragma unroll
        for (int i = 0; i < 8; ++i) {
            const int pos = m0 + wr * 128 + i * 16 + l15;
            if (pos < Me) {
                const int token = idxE[i];
                const float w = mw[(size_t)token * 8 + e0];
                unsigned short* crow = Cg + (size_t)token * ldc + n0;
#pragma unroll
                for (int j = 0; j < 4; ++j) {
                    const int n = wc * 64 + j * 16 + nr0v;
                    us4 o;
#pragma unroll
                    for (int r = 0; r < 4; ++r)
                        o[r] = f2bf(w * gelu_fast(acc[i][j][r] + b1v[j][r]));
                    *(us4*)(crow + n) = o;
                }
            }
        }
    } else {
#pragma unroll
        for (int i = 0; i < 8; ++i) {
            const int row = m0 + wr * 128 + i * 16 + l15;
            float* cp = Cacc + (size_t)row * 1024 + n0;
#pragma unroll
            for (int j = 0; j < 4; ++j) {
                const int n = wc * 64 + j * 16 + nr0v;
                if (init) {
                    *(f32x4*)(cp + n) = acc[i][j];
                } else {
                    f32x4 old = *(const f32x4*)(cp + n);
                    *(f32x4*)(cp + n) = old + acc[i][j];
                }
            }
        }
    }
}

// ------------- Combine: out = sum_z part[z] + sum_e mw*b2 --------------------
__global__ __launch_bounds__(256) void moe_combine_kernel(
    const float* __restrict__ part, int S,
    float* __restrict__ out, const float* __restrict__ mw,
    const float* __restrict__ b2)
{
    const int n = blockIdx.x, t = threadIdx.x;
    const int d = t * 4;
    f32x4 v = *(const f32x4*)(part + (size_t)n * 1024 + d);
    for (int z = 1; z < S; ++z)
        v = v + *(const f32x4*)(part + (size_t)z * (8192 * 1024) + (size_t)n * 1024 + d);
#pragma unroll
    for (int e = 0; e < 8; ++e) {
        const float w = mw[(size_t)n * 8 + e];
        const f32x4 b = *(const f32x4*)(b2 + (size_t)e * 1024 + d);
        v = v + w * b;
    }
    *(f32x4*)(out + (size_t)n * 1024 + d) = v;
}

extern "C" void kernel_launch(void* const* d_in, const int* in_sizes, int n_in,
                              void* d_out, int out_size, void* d_ws, size_t ws_size,
                              hipStream_t stream)
{
    (void)in_sizes; (void)n_in; (void)out_size;
    const float* h  = (const float*)d_in[0];
    const float* Wr = (const float*)d_in[1];
    const float* br = (const float*)d_in[2];
    const float* W1 = (const float*)d_in[3];
    const float* b1 = (const float*)d_in[4];
    const float* W2 = (const float*)d_in[5];
    const float* b2 = (const float*)d_in[6];
    float* out = (float*)d_out;   // fp32 output [N][D]

    const int N = 8192, D = 1024, F = 4096, E = 8;
    const int S = 2;
    auto al = [](size_t x) { return (x + 255) & ~(size_t)255; };
    const size_t sz_hbf = al((size_t)N * D * 2);
    const size_t sz_mw  = al((size_t)N * E * 4);
    const size_t sz_cnt = al(8 * 4);
    const size_t sz_seg = al(8 * 32 * 4);
    const size_t sz_tok = al((size_t)N * E * 4);
    const size_t sz_pt1 = al((size_t)N * D * 4);
    auto tot = [&](int fc) {
        size_t s = sz_hbf + sz_mw + sz_cnt + 2 * sz_seg + sz_tok
                 + al((size_t)N * ((size_t)E * fc + 32) * 2)
                 + al((size_t)E * fc * D * 2) * 2
                 + (size_t)S * sz_pt1;
        return s;
    };
    // Fc=1024 preferred: Fc=2048's 64-panel MODE0 geometry blows the 4 MB
    // per-XCD L2 (measured FETCH 100 -> 169 MB, +45% per-block time).
    int Fc;
    if      (tot(1024) <= ws_size) Fc = 1024;
    else if (tot(512)  <= ws_size) Fc = 512;
    else                           Fc = 256;
    const int logFc = (Fc == 1024) ? 10 : (Fc == 512) ? 9 : 8;
    const int Kc = E * Fc;
    const int ldAp = Kc + 32;   // padded ghid pitch (breaks pow2 row alias)

    char* p = (char*)d_ws;
    unsigned short* hbf = (unsigned short*)p; p += sz_hbf;
    float* mwp  = (float*)p; p += sz_mw;
    int*   cnt  = (int*)p;   p += sz_cnt;
    int*   bcnt = (int*)p;   p += sz_seg;
    int*   bbas = (int*)p;   p += sz_seg;
    int*   tok  = (int*)p;   p += sz_tok;
    unsigned short* ghid = (unsigned short*)p; p += al((size_t)N * (size_t)ldAp * 2);
    unsigned short* W1t  = (unsigned short*)p; p += al((size_t)E * Fc * D * 2);
    unsigned short* W2t  = (unsigned short*)p; p += al((size_t)E * Fc * D * 2);
    float* part = (float*)p;

    moe_router_kernel<<<N / 4, 256, 0, stream>>>(h, Wr, br, hbf, mwp);
    moe_cnt_kernel<<<N / 256, 256, 0, stream>>>(mwp, bcnt);
    moe_scan_kernel<<<1, 64, 0, stream>>>(bcnt, bbas, cnt);
    moe_place_kernel<<<N / 256, 256, 0, stream>>>(mwp, bbas, tok);
    moe_zfill_kernel<<<N, 256, 0, stream>>>(mwp, ghid, Fc, ldAp);

    const int nch = F / Fc;
    for (int c = 0; c < nch; ++c) {
        // chunk-local transposed bf16 weights
        moe_tcvt_kernel<<<dim3(D / 32, Fc / 32, E), 256, 0, stream>>>(
            W1 + (size_t)c * Fc, W1t, F, (size_t)D * F, D, (size_t)Fc * D);
        moe_tcvt_kernel<<<dim3(Fc / 32, D / 32, E), 256, 0, stream>>>(
            W2 + (size_t)c * Fc * D, W2t, D, (size_t)F * D, Fc, (size_t)D * Fc);

        moe_gemm8p<0><<<dim3(32, Kc / 256, 1), 512, 0, stream>>>(
            hbf, 1024, W1t, (size_t)Fc * D, 1024, b1, mwp, ghid, ldAp, nullptr,
            cnt, tok, logFc, c * Fc, /*kspan=*/1024, 0);

        moe_gemm8p<1><<<dim3(32, 4, S), 512, 0, stream>>>(
            ghid, ldAp, W2t, (size_t)D * Fc, Fc, nullptr, nullptr, nullptr, 0, part,
            nullptr, nullptr, logFc, 0, /*kspan=*/Kc / S, (c == 0) ? 1 : 0);
    }

    moe_combine_kernel<<<N, 256, 0, stream>>>(part, S, out, mwp, b2);
}

// Round 14
// 1296.192 us; speedup vs baseline: 1.0052x; 1.0052x over previous
//
#include <hip/hip_runtime.h>
#include <hip/hip_bf16.h>
#include <cstdint>
#include <cstddef>

typedef __attribute__((ext_vector_type(8))) __bf16 bf16x8;
typedef __attribute__((ext_vector_type(4))) float f32x4;
typedef __attribute__((ext_vector_type(4))) unsigned short us4;

#define GLOAD_LDS16(g, l)                                                        \
    __builtin_amdgcn_global_load_lds(                                            \
        (const __attribute__((address_space(1))) void*)(g),                      \
        (__attribute__((address_space(3))) void*)(l), 16, 0, 0)

static __device__ __forceinline__ unsigned short f2bf(float x) {
    unsigned int u = __builtin_bit_cast(unsigned int, x);
    return (unsigned short)((u + 0x7FFFu + ((u >> 16) & 1u)) >> 16);
}

// gelu(x) = x * sigmoid(1.5957691x + 0.0713548x^3)  (== tanh-form gelu)
static __device__ __forceinline__ float gelu_fast(float x) {
    const float p = x * x;
    const float u = x * fmaf(0.0713548162726f, p, 1.59576912161f);
    const float t = __expf(-u);
    return x * __builtin_amdgcn_rcpf(1.0f + t);
}

// ---------------- Router: logits -> softmax -> mask, plus h -> bf16 ----------
__global__ __launch_bounds__(256) void moe_router_kernel(
    const float* __restrict__ h, const float* __restrict__ Wr,
    const float* __restrict__ br, unsigned short* __restrict__ hbf,
    float* __restrict__ mw)
{
    const int lane = threadIdx.x & 63, wave = threadIdx.x >> 6;
    const int n = blockIdx.x * 4 + wave;  // one token per wave
    const float* hr = h + (size_t)n * 1024;
    const int base = lane * 16;

    float xs[16];
#pragma unroll
    for (int q = 0; q < 4; ++q) {
        f32x4 v = *(const f32x4*)(hr + base + q * 4);
        xs[q * 4 + 0] = v[0]; xs[q * 4 + 1] = v[1];
        xs[q * 4 + 2] = v[2]; xs[q * 4 + 3] = v[3];
    }
    float acc[8] = {0.f, 0.f, 0.f, 0.f, 0.f, 0.f, 0.f, 0.f};
#pragma unroll
    for (int j = 0; j < 16; ++j) {
        const float x = xs[j];
        const f32x4 w0 = *(const f32x4*)(Wr + (size_t)(base + j) * 8);
        const f32x4 w1 = *(const f32x4*)(Wr + (size_t)(base + j) * 8 + 4);
        acc[0] += x * w0[0]; acc[1] += x * w0[1]; acc[2] += x * w0[2]; acc[3] += x * w0[3];
        acc[4] += x * w1[0]; acc[5] += x * w1[1]; acc[6] += x * w1[2]; acc[7] += x * w1[3];
    }
#pragma unroll
    for (int q = 0; q < 4; ++q) {
        us4 o;
        o[0] = f2bf(xs[q * 4 + 0]); o[1] = f2bf(xs[q * 4 + 1]);
        o[2] = f2bf(xs[q * 4 + 2]); o[3] = f2bf(xs[q * 4 + 3]);
        *(us4*)(hbf + (size_t)n * 1024 + base + q * 4) = o;
    }
#pragma unroll
    for (int m = 32; m >= 1; m >>= 1)
#pragma unroll
        for (int e = 0; e < 8; ++e) acc[e] += __shfl_xor(acc[e], m, 64);

    if (lane == 0) {
        float l[8]; float mx = -1e30f;
#pragma unroll
        for (int e = 0; e < 8; ++e) { l[e] = acc[e] + br[e]; mx = fmaxf(mx, l[e]); }
        float s = 0.f;
#pragma unroll
        for (int e = 0; e < 8; ++e) { l[e] = __expf(l[e] - mx); s += l[e]; }
        const float inv = 1.0f / s;
#pragma unroll
        for (int e = 0; e < 8; ++e) {
            const float w = l[e] * inv;
            mw[(size_t)n * 8 + e] = (w > 0.05f) ? w : 0.0f;
        }
    }
}

// ----- Deterministic sorted compaction: count -> scan -> place ---------------
__global__ __launch_bounds__(256) void moe_cnt_kernel(
    const float* __restrict__ mw, int* __restrict__ blkcnt)   // [8][32]
{
    const int blk = blockIdx.x;
    const int n = blk * 256 + threadIdx.x;
    const int lane = threadIdx.x & 63, wv = threadIdx.x >> 6;
    __shared__ int wcnt[8][4];
#pragma unroll
    for (int e = 0; e < 8; ++e) {
        const unsigned long long m = __ballot(mw[(size_t)n * 8 + e] > 0.f);
        if (lane == 0) wcnt[e][wv] = __popcll(m);
    }
    __syncthreads();
    if (threadIdx.x < 8)
        blkcnt[threadIdx.x * 32 + blk] =
            wcnt[threadIdx.x][0] + wcnt[threadIdx.x][1] +
            wcnt[threadIdx.x][2] + wcnt[threadIdx.x][3];
}

__global__ __launch_bounds__(64) void moe_scan_kernel(
    const int* __restrict__ blkcnt, int* __restrict__ blkbase, int* __restrict__ cnt)
{
    const int e = threadIdx.x;
    if (e < 8) {
        int s = 0;
        for (int b = 0; b < 32; ++b) {
            blkbase[e * 32 + b] = s;
            s += blkcnt[e * 32 + b];
        }
        cnt[e] = s;
    }
}

__global__ __launch_bounds__(256) void moe_place_kernel(
    const float* __restrict__ mw, const int* __restrict__ blkbase,
    int* __restrict__ toklist)
{
    const int blk = blockIdx.x;
    const int n = blk * 256 + threadIdx.x;
    const int lane = threadIdx.x & 63, wv = threadIdx.x >> 6;
    __shared__ int wbase[8][4];
    unsigned long long msk[8];
#pragma unroll
    for (int e = 0; e < 8; ++e) {
        msk[e] = __ballot(mw[(size_t)n * 8 + e] > 0.f);
        if (lane == 0) wbase[e][wv] = __popcll(msk[e]);
    }
    __syncthreads();
    if (threadIdx.x < 8) {
        int s = blkbase[threadIdx.x * 32 + blk];
#pragma unroll
        for (int w = 0; w < 4; ++w) {
            const int c = wbase[threadIdx.x][w];
            wbase[threadIdx.x][w] = s;
            s += c;
        }
    }
    __syncthreads();
#pragma unroll
    for (int e = 0; e < 8; ++e) {
        if (msk[e] & (1ull << lane)) {
            const int pre = __popcll(msk[e] & ((1ull << lane) - 1ull));
            toklist[e * 8192 + wbase[e][wv] + pre] = n;
        }
    }
}

// -------- Zero-fill inactive ghid rows (once; inactive set fixed per call) ---
__global__ __launch_bounds__(256) void moe_zfill_kernel(
    const float* __restrict__ mw, unsigned short* __restrict__ ghid,
    int Fc, int ldAp)
{
    const int n = blockIdx.x, t = threadIdx.x;
    __shared__ float w[8];
    if (t < 8) w[t] = mw[(size_t)n * 8 + t];
    __syncthreads();
    const us4 z = {0, 0, 0, 0};
#pragma unroll
    for (int e = 0; e < 8; ++e) {
        if (w[e] == 0.f) {
            unsigned short* row = ghid + (size_t)n * ldAp + e * Fc;
            for (int c = t * 4; c < Fc; c += 1024)
                *(us4*)(row + c) = z;
        }
    }
}

// ---------- Transpose + fp32->bf16 convert (32x32 tiles, per expert z) -------
__global__ __launch_bounds__(256) void moe_tcvt_kernel(
    const float* __restrict__ in, unsigned short* __restrict__ out,
    int ls, size_t in_es, int os, size_t out_es)
{
    __shared__ unsigned short t[32][33];
    const int e = blockIdx.z;
    const int r = threadIdx.x >> 3, c = (threadIdx.x & 7) * 4;
    const float* I = in + (size_t)e * in_es + (size_t)(blockIdx.x * 32 + r) * ls + blockIdx.y * 32 + c;
    f32x4 v = *(const f32x4*)I;
    t[r][c + 0] = f2bf(v[0]); t[r][c + 1] = f2bf(v[1]);
    t[r][c + 2] = f2bf(v[2]); t[r][c + 3] = f2bf(v[3]);
    __syncthreads();
    unsigned short* O = out + (size_t)e * out_es + (size_t)(blockIdx.y * 32 + r) * os + blockIdx.x * 32 + c;
    us4 o;
    o[0] = t[c + 0][r]; o[1] = t[c + 1][r]; o[2] = t[c + 2][r]; o[3] = t[c + 3][r];
    *(us4*)O = o;
}

// ============ 8-phase 256x256 GEMM, BK=64, look-ahead ds_read pipeline =======
// MODE 0 (sorted token-compacted, XCD-interleaved): bx = (j&3)*8 + c8 so each
//   XCD owns stride-8 position slices of the active prefix -> balanced
//   early-exit.  ghid = mw * gelu(hbf @ W1t^T + b1)
// MODE 1: part[z] (+)= ghid[:, klo:klo+kspan] @ W2t^T   (fp32 RMW, dense)
#define MFMA_QUAD(MB, NB, AF, BQ)                                              \
  _Pragma("unroll") for (int mi_ = 0; mi_ < 4; ++mi_)                          \
  _Pragma("unroll") for (int ni_ = 0; ni_ < 2; ++ni_) {                        \
      acc[(MB)+mi_][(NB)+ni_] = __builtin_amdgcn_mfma_f32_16x16x32_bf16(       \
          BQ[ni_][1], AF[mi_][1], __builtin_amdgcn_mfma_f32_16x16x32_bf16(     \
          BQ[ni_][0], AF[mi_][0], acc[(MB)+mi_][(NB)+ni_], 0, 0, 0), 0, 0, 0); \
  }

#define BARX()   __builtin_amdgcn_s_barrier()
#define SBX()    __builtin_amdgcn_sched_barrier(0)
#define LGKM(N)  asm volatile("s_waitcnt lgkmcnt(" #N ")" ::: "memory")
#define VMC(N)   asm volatile("s_waitcnt vmcnt(" #N ")" ::: "memory")
#define PRIO1()  __builtin_amdgcn_s_setprio(1)
#define PRIO0()  __builtin_amdgcn_s_setprio(0)

template <int MODE>
__global__ __launch_bounds__(512) void moe_gemm8p(
    const unsigned short* __restrict__ A, int ldga,
    const unsigned short* __restrict__ Bbase, size_t estride, int ldb,
    const float* __restrict__ b1, const float* __restrict__ mw,
    unsigned short* __restrict__ Cg, int ldc,
    float* __restrict__ part,
    const int* __restrict__ cnt, const int* __restrict__ toklist,
    int logFc, int f0glob, int kspan, int init)
{
    __shared__ unsigned short sh[65536];   // 128 KiB: XA,XB,YA,YB (32KB each)
    char* sm = (char*)sh;
    const int XA = 0, XB = 32768, YA = 65536, YB = 98304;

    const int tid = threadIdx.x, lane = tid & 63, wv = tid >> 6;
    const int wr = wv >> 2, wc = wv & 3;

    // XCD-affine bijective block mapping (flat id % 8 == XCD).
    int bx, by;
    if constexpr (MODE == 0) {
        const int orig = blockIdx.x + blockIdx.y * 32;  // [0, 32*gy)
        const int c8 = orig & 7, j = orig >> 3;
        bx = (j & 3) * 8 + c8;   // stride-8 interleave: balanced active prefix
        by = j >> 2;
    } else {
        const int orig = blockIdx.x + blockIdx.y * 32;  // [0,128)
        const int c8 = orig & 7, j = orig >> 3;         // [0,16)
        bx = c8 * 4 + (j >> 2); by = j & 3;
    }
    const int m0 = bx * 256;
    const int n0 = by * 256;

    const int z = (MODE == 1) ? blockIdx.z : 0;
    const int klo = z * kspan;
    float* Cacc = (MODE == 1) ? part + (size_t)z * (8192 * 1024) : nullptr;

    // MODE0 fixed expert / B base
    int e0 = 0, fb = 0;
    const unsigned short* gB0 = nullptr;
    const int rl0 = tid >> 3;                          // row [0,64)
    const int gs8 = ((tid & 7) ^ (rl0 & 7)) * 8;       // XOR-swizzled src col
    const int l15 = lane & 15, l4 = lane >> 4, l7 = lane & 7;

    int Me = 0;
    int idxS[4], idxE[8];
    if constexpr (MODE == 0) {
        e0 = n0 >> logFc; fb = n0 - (e0 << logFc);
        gB0 = Bbase + (size_t)e0 * estride + (size_t)(fb + rl0) * ldb + gs8;
        Me = cnt[e0];
        if (m0 >= Me) return;                  // uniform early-exit
        const int* tl = toklist + e0 * 8192;
#pragma unroll
        for (int q = 0; q < 4; ++q) {
            int pos = m0 + rl0 + q * 64; if (pos > Me - 1) pos = Me - 1;
            idxS[q] = tl[pos];
        }
#pragma unroll
        for (int i = 0; i < 8; ++i) {
            int pos = m0 + wr * 128 + i * 16 + l15; if (pos > Me - 1) pos = Me - 1;
            idxE[i] = tl[pos];
        }
        VMC(0); SBX();                         // keep vmcnt ledger clean
    }
    const unsigned short* gA0 = A + (size_t)(m0 + rl0) * ldga + gs8;
    const int dstw = wv * 1024;

    auto stageA = [&](int reg, int kk, int q) {
        const unsigned short* ga;
        if constexpr (MODE == 0) {
            ga = A + (size_t)idxS[q] * ldga + gs8 + kk;
        } else {
            ga = gA0 + kk + (size_t)(q * 64) * ldga;
        }
        GLOAD_LDS16(ga, sm + reg + (q >> 1) * 16384 + (q & 1) * 8192 + dstw);
    };
    auto stageB = [&](int reg, int kk, int q) {
        const unsigned short* gb;
        if constexpr (MODE == 0) {
            gb = gB0 + kk;
        } else {
            const int e = kk >> logFc, kc = kk - (e << logFc);
            gb = Bbase + (size_t)e * estride + (size_t)(n0 + rl0) * ldb + kc + gs8;
        }
        GLOAD_LDS16(gb + (size_t)(q * 64) * ldb,
                    sm + reg + (q >> 1) * 16384 + (q & 1) * 8192 + dstw);
    };

    // ds_read swizzled addresses
    const int sA0 = (wr * 128 + l15) * 128 + (((0 + l4) ^ l7) << 4);
    const int sA1 = (wr * 128 + l15) * 128 + (((4 + l4) ^ l7) << 4);
    const int sB0 = (wc * 64 + l15) * 128 + (((0 + l4) ^ l7) << 4);
    const int sB1 = (wc * 64 + l15) * 128 + (((4 + l4) ^ l7) << 4);

    f32x4 acc[8][4] = {};
    bf16x8 afL[4][2], afH[4][2], bqL[2][2], bqH[2][2];

#define RD_AFL(BASE) _Pragma("unroll") for (int mi_=0;mi_<4;++mi_){            \
      afL[mi_][0] = *(const bf16x8*)(sm + (BASE) + sA0 + mi_*2048);            \
      afL[mi_][1] = *(const bf16x8*)(sm + (BASE) + sA1 + mi_*2048); }
#define RD_AFH(BASE) _Pragma("unroll") for (int mi_=0;mi_<4;++mi_){            \
      afH[mi_][0] = *(const bf16x8*)(sm + (BASE) + sA0 + (4+mi_)*2048);        \
      afH[mi_][1] = *(const bf16x8*)(sm + (BASE) + sA1 + (4+mi_)*2048); }
#define RD_BQL(BASE) _Pragma("unroll") for (int ni_=0;ni_<2;++ni_){            \
      bqL[ni_][0] = *(const bf16x8*)(sm + (BASE) + sB0 + ni_*2048);            \
      bqL[ni_][1] = *(const bf16x8*)(sm + (BASE) + sB1 + ni_*2048); }
#define RD_BQH(BASE) _Pragma("unroll") for (int ni_=0;ni_<2;++ni_){            \
      bqH[ni_][0] = *(const bf16x8*)(sm + (BASE) + sB0 + (2+ni_)*2048);        \
      bqH[ni_][1] = *(const bf16x8*)(sm + (BASE) + sB1 + (2+ni_)*2048); }

    const int niter = kspan >> 7;  // 2 K-tiles (2x64) per iteration

    // Prologue: stage X(t0), Y(t1); drain X; read X Q1 frags after barrier.
#pragma unroll
    for (int q = 0; q < 4; ++q) { stageA(XA, klo, q); stageB(XB, klo, q); }
#pragma unroll
    for (int q = 0; q < 4; ++q) { stageA(YA, klo + 64, q); stageB(YB, klo + 64, q); }
    VMC(8); SBX();
    BARX();
    RD_AFL(XA); RD_BQL(XB);

    for (int it = 0; it < niter; ++it) {
        const int kX2 = klo + it * 128 + 128;  // next X tile
        const int kY2 = klo + it * 128 + 192;  // next Y tile
        const bool g = (it + 1 < niter);
        // ---- P1: MFMA Q1(X); read-ahead bqH(X)
        RD_BQH(XB);
        BARX(); LGKM(4); SBX(); PRIO1(); MFMA_QUAD(0, 0, afL, bqL); PRIO0(); BARX();
        // ---- P2: MFMA Q2(X); read-ahead afH(X); stage nextX A q0,q2
        RD_AFH(XA);
        if (g) { stageA(XA, kX2, 0); stageA(XA, kX2, 2); }
        BARX(); LGKM(8); SBX(); PRIO1(); MFMA_QUAD(0, 2, afL, bqH); PRIO0(); BARX();
        // ---- P3: MFMA Q3(X); stage nextX B q0,q1
        if (g) { stageB(XB, kX2, 0); stageB(XB, kX2, 1); }
        BARX(); LGKM(0); SBX(); PRIO1(); MFMA_QUAD(4, 0, afH, bqL); PRIO0(); BARX();
        // ---- P4: stage nextX rest; vmcnt; barrier; read Y Q1; MFMA Q4(X)
        if (g) { stageA(XA, kX2, 1); stageA(XA, kX2, 3);
                 stageB(XB, kX2, 2); stageB(XB, kX2, 3);
                 VMC(8); } else { VMC(0); }
        SBX();
        BARX();
        RD_AFL(YA); RD_BQL(YB);
        SBX(); PRIO1(); MFMA_QUAD(4, 2, afH, bqH); PRIO0(); BARX();
        // ---- P5: MFMA Q1(Y); read-ahead bqH(Y)
        RD_BQH(YB);
        BARX(); LGKM(4); SBX(); PRIO1(); MFMA_QUAD(0, 0, afL, bqL); PRIO0(); BARX();
        // ---- P6: MFMA Q2(Y); read-ahead afH(Y); stage nextY A q0,q2
        RD_AFH(YA);
        if (g) { stageA(YA, kY2, 0); stageA(YA, kY2, 2); }
        BARX(); LGKM(8); SBX(); PRIO1(); MFMA_QUAD(0, 2, afL, bqH); PRIO0(); BARX();
        // ---- P7: MFMA Q3(Y); stage nextY B q0,q1
        if (g) { stageB(YB, kY2, 0); stageB(YB, kY2, 1); }
        BARX(); LGKM(0); SBX(); PRIO1(); MFMA_QUAD(4, 0, afH, bqL); PRIO0(); BARX();
        // ---- P8: stage nextY rest; vmcnt; barrier; read nextX Q1; MFMA Q4(Y)
        if (g) { stageA(YA, kY2, 1); stageA(YA, kY2, 3);
                 stageB(YB, kY2, 2); stageB(YB, kY2, 3);
                 VMC(8); } else { VMC(0); }
        SBX();
        BARX();
        if (g) { RD_AFL(XA); RD_BQL(XB); }
        SBX(); PRIO1(); MFMA_QUAD(4, 2, afH, bqH); PRIO0(); BARX();
    }

    // Epilogue
    const int nr0v = l4 * 4;
    if constexpr (MODE == 0) {
        const float* b1p = b1 + (size_t)e0 * 4096 + f0glob + fb;
        f32x4 b1v[4];
#pragma unroll
        for (int j = 0; j < 4; ++j)
            b1v[j] = *(const f32x4*)(b1p + wc * 64 + j * 16 + nr0v);
#pragma unroll
        for (int i = 0; i < 8; ++i) {
            const int pos = m0 + wr * 128 + i * 16 + l15;
            if (pos < Me) {
                const int token = idxE[i];
                const float w = mw[(size_t)token * 8 + e0];
                unsigned short* crow = Cg + (size_t)token * ldc + n0;
#pragma unroll
                for (int j = 0; j < 4; ++j) {
                    const int n = wc * 64 + j * 16 + nr0v;
                    us4 o;
#pragma unroll
                    for (int r = 0; r < 4; ++r)
                        o[r] = f2bf(w * gelu_fast(acc[i][j][r] + b1v[j][r]));
                    *(us4*)(crow + n) = o;
                }
            }
        }
    } else {
#pragma unroll
        for (int i = 0; i < 8; ++i) {
            const int row = m0 + wr * 128 + i * 16 + l15;
            float* cp = Cacc + (size_t)row * 1024 + n0;
#pragma unroll
            for (int j = 0; j < 4; ++j) {
                const int n = wc * 64 + j * 16 + nr0v;
                if (init) {
                    *(f32x4*)(cp + n) = acc[i][j];
                } else {
                    f32x4 old = *(const f32x4*)(cp + n);
                    *(f32x4*)(cp + n) = old + acc[i][j];
                }
            }
        }
    }
}

// ------------- Combine: out = sum_z part[z] + sum_e mw*b2 --------------------
__global__ __launch_bounds__(256) void moe_combine_kernel(
    const float* __restrict__ part, int S,
    float* __restrict__ out, const float* __restrict__ mw,
    const float* __restrict__ b2)
{
    const int n = blockIdx.x, t = threadIdx.x;
    const int d = t * 4;
    f32x4 v = *(const f32x4*)(part + (size_t)n * 1024 + d);
    for (int z = 1; z < S; ++z)
        v = v + *(const f32x4*)(part + (size_t)z * (8192 * 1024) + (size_t)n * 1024 + d);
#pragma unroll
    for (int e = 0; e < 8; ++e) {
        const float w = mw[(size_t)n * 8 + e];
        const f32x4 b = *(const f32x4*)(b2 + (size_t)e * 1024 + d);
        v = v + w * b;
    }
    *(f32x4*)(out + (size_t)n * 1024 + d) = v;
}

extern "C" void kernel_launch(void* const* d_in, const int* in_sizes, int n_in,
                              void* d_out, int out_size, void* d_ws, size_t ws_size,
                              hipStream_t stream)
{
    (void)in_sizes; (void)n_in; (void)out_size;
    const float* h  = (const float*)d_in[0];
    const float* Wr = (const float*)d_in[1];
    const float* br = (const float*)d_in[2];
    const float* W1 = (const float*)d_in[3];
    const float* b1 = (const float*)d_in[4];
    const float* W2 = (const float*)d_in[5];
    const float* b2 = (const float*)d_in[6];
    float* out = (float*)d_out;   // fp32 output [N][D]

    const int N = 8192, D = 1024, F = 4096, E = 8;
    const int S = 2;
    auto al = [](size_t x) { return (x + 255) & ~(size_t)255; };
    const size_t sz_hbf = al((size_t)N * D * 2);
    const size_t sz_mw  = al((size_t)N * E * 4);
    const size_t sz_cnt = al(8 * 4);
    const size_t sz_seg = al(8 * 32 * 4);
    const size_t sz_tok = al((size_t)N * E * 4);
    const size_t sz_pt1 = al((size_t)N * D * 4);
    auto tot = [&](int fc) {
        size_t s = sz_hbf + sz_mw + sz_cnt + 2 * sz_seg + sz_tok
                 + al((size_t)N * ((size_t)E * fc + 32) * 2)
                 + al((size_t)E * fc * D * 2) * 2
                 + (size_t)S * sz_pt1;
        return s;
    };
    // Fc=1024: Fc=2048's 64-panel MODE0 geometry blows the 4 MB per-XCD L2.
    int Fc;
    if      (tot(1024) <= ws_size) Fc = 1024;
    else if (tot(512)  <= ws_size) Fc = 512;
    else                           Fc = 256;
    const int logFc = (Fc == 1024) ? 10 : (Fc == 512) ? 9 : 8;
    const int Kc = E * Fc;
    const int ldAp = Kc + 32;   // padded ghid pitch (breaks pow2 row alias)

    char* p = (char*)d_ws;
    unsigned short* hbf = (unsigned short*)p; p += sz_hbf;
    float* mwp  = (float*)p; p += sz_mw;
    int*   cnt  = (int*)p;   p += sz_cnt;
    int*   bcnt = (int*)p;   p += sz_seg;
    int*   bbas = (int*)p;   p += sz_seg;
    int*   tok  = (int*)p;   p += sz_tok;
    unsigned short* ghid = (unsigned short*)p; p += al((size_t)N * (size_t)ldAp * 2);
    unsigned short* W1t  = (unsigned short*)p; p += al((size_t)E * Fc * D * 2);
    unsigned short* W2t  = (unsigned short*)p; p += al((size_t)E * Fc * D * 2);
    float* part = (float*)p;

    moe_router_kernel<<<N / 4, 256, 0, stream>>>(h, Wr, br, hbf, mwp);
    moe_cnt_kernel<<<N / 256, 256, 0, stream>>>(mwp, bcnt);
    moe_scan_kernel<<<1, 64, 0, stream>>>(bcnt, bbas, cnt);
    moe_place_kernel<<<N / 256, 256, 0, stream>>>(mwp, bbas, tok);
    moe_zfill_kernel<<<N, 256, 0, stream>>>(mwp, ghid, Fc, ldAp);

    const int nch = F / Fc;
    for (int c = 0; c < nch; ++c) {
        // chunk-local transposed bf16 weights
        moe_tcvt_kernel<<<dim3(D / 32, Fc / 32, E), 256, 0, stream>>>(
            W1 + (size_t)c * Fc, W1t, F, (size_t)D * F, D, (size_t)Fc * D);
        moe_tcvt_kernel<<<dim3(Fc / 32, D / 32, E), 256, 0, stream>>>(
            W2 + (size_t)c * Fc * D, W2t, D, (size_t)F * D, Fc, (size_t)D * Fc);

        moe_gemm8p<0><<<dim3(32, Kc / 256, 1), 512, 0, stream>>>(
            hbf, 1024, W1t, (size_t)Fc * D, 1024, b1, mwp, ghid, ldAp, nullptr,
            cnt, tok, logFc, c * Fc, /*kspan=*/1024, 0);

        moe_gemm8p<1><<<dim3(32, 4, S), 512, 0, stream>>>(
            ghid, ldAp, W2t, (size_t)D * Fc, Fc, nullptr, nullptr, nullptr, 0, part,
            nullptr, nullptr, logFc, 0, /*kspan=*/Kc / S, (c == 0) ? 1 : 0);
    }

    moe_combine_kernel<<<N, 256, 0, stream>>>(part, S, out, mwp, b2);
}

// Round 15
// 1242.894 us; speedup vs baseline: 1.0483x; 1.0429x over previous
//
#include <hip/hip_runtime.h>
#include <hip/hip_bf16.h>
#include <cstdint>
#include <cstddef>

typedef __attribute__((ext_vector_type(8))) __bf16 bf16x8;
typedef __attribute__((ext_vector_type(4))) float f32x4;
typedef __attribute__((ext_vector_type(4))) unsigned short us4;

#define GLOAD_LDS16(g, l)                                                        \
    __builtin_amdgcn_global_load_lds(                                            \
        (const __attribute__((address_space(1))) void*)(g),                      \
        (__attribute__((address_space(3))) void*)(l), 16, 0, 0)

static __device__ __forceinline__ unsigned short f2bf(float x) {
    unsigned int u = __builtin_bit_cast(unsigned int, x);
    return (unsigned short)((u + 0x7FFFu + ((u >> 16) & 1u)) >> 16);
}

// gelu(x) = x * sigmoid(1.5957691x + 0.0713548x^3)  (== tanh-form gelu)
static __device__ __forceinline__ float gelu_fast(float x) {
    const float p = x * x;
    const float u = x * fmaf(0.0713548162726f, p, 1.59576912161f);
    const float t = __expf(-u);
    return x * __builtin_amdgcn_rcpf(1.0f + t);
}

// ---------------- Router: logits -> softmax -> mask, plus h -> bf16 ----------
__global__ __launch_bounds__(256) void moe_router_kernel(
    const float* __restrict__ h, const float* __restrict__ Wr,
    const float* __restrict__ br, unsigned short* __restrict__ hbf,
    float* __restrict__ mw)
{
    const int lane = threadIdx.x & 63, wave = threadIdx.x >> 6;
    const int n = blockIdx.x * 4 + wave;  // one token per wave
    const float* hr = h + (size_t)n * 1024;
    const int base = lane * 16;

    float xs[16];
#pragma unroll
    for (int q = 0; q < 4; ++q) {
        f32x4 v = *(const f32x4*)(hr + base + q * 4);
        xs[q * 4 + 0] = v[0]; xs[q * 4 + 1] = v[1];
        xs[q * 4 + 2] = v[2]; xs[q * 4 + 3] = v[3];
    }
    float acc[8] = {0.f, 0.f, 0.f, 0.f, 0.f, 0.f, 0.f, 0.f};
#pragma unroll
    for (int j = 0; j < 16; ++j) {
        const float x = xs[j];
        const f32x4 w0 = *(const f32x4*)(Wr + (size_t)(base + j) * 8);
        const f32x4 w1 = *(const f32x4*)(Wr + (size_t)(base + j) * 8 + 4);
        acc[0] += x * w0[0]; acc[1] += x * w0[1]; acc[2] += x * w0[2]; acc[3] += x * w0[3];
        acc[4] += x * w1[0]; acc[5] += x * w1[1]; acc[6] += x * w1[2]; acc[7] += x * w1[3];
    }
#pragma unroll
    for (int q = 0; q < 4; ++q) {
        us4 o;
        o[0] = f2bf(xs[q * 4 + 0]); o[1] = f2bf(xs[q * 4 + 1]);
        o[2] = f2bf(xs[q * 4 + 2]); o[3] = f2bf(xs[q * 4 + 3]);
        *(us4*)(hbf + (size_t)n * 1024 + base + q * 4) = o;
    }
#pragma unroll
    for (int m = 32; m >= 1; m >>= 1)
#pragma unroll
        for (int e = 0; e < 8; ++e) acc[e] += __shfl_xor(acc[e], m, 64);

    if (lane == 0) {
        float l[8]; float mx = -1e30f;
#pragma unroll
        for (int e = 0; e < 8; ++e) { l[e] = acc[e] + br[e]; mx = fmaxf(mx, l[e]); }
        float s = 0.f;
#pragma unroll
        for (int e = 0; e < 8; ++e) { l[e] = __expf(l[e] - mx); s += l[e]; }
        const float inv = 1.0f / s;
#pragma unroll
        for (int e = 0; e < 8; ++e) {
            const float w = l[e] * inv;
            mw[(size_t)n * 8 + e] = (w > 0.05f) ? w : 0.0f;
        }
    }
}

// ---------- Transpose + fp32->bf16 convert (32x32 tiles, per expert z) -------
__global__ __launch_bounds__(256) void moe_tcvt_kernel(
    const float* __restrict__ in, unsigned short* __restrict__ out,
    int ls, size_t in_es, int os, size_t out_es)
{
    __shared__ unsigned short t[32][33];
    const int e = blockIdx.z;
    const int r = threadIdx.x >> 3, c = (threadIdx.x & 7) * 4;
    const float* I = in + (size_t)e * in_es + (size_t)(blockIdx.x * 32 + r) * ls + blockIdx.y * 32 + c;
    f32x4 v = *(const f32x4*)I;
    t[r][c + 0] = f2bf(v[0]); t[r][c + 1] = f2bf(v[1]);
    t[r][c + 2] = f2bf(v[2]); t[r][c + 3] = f2bf(v[3]);
    __syncthreads();
    unsigned short* O = out + (size_t)e * out_es + (size_t)(blockIdx.y * 32 + r) * os + blockIdx.x * 32 + c;
    us4 o;
    o[0] = t[c + 0][r]; o[1] = t[c + 1][r]; o[2] = t[c + 2][r]; o[3] = t[c + 3][r];
    *(us4*)O = o;
}

// ============ 8-phase 256x256 GEMM, BK=64, look-ahead ds_read pipeline =======
// MODE 0: ghid = mw * gelu(hbf @ W1t^T + b1)    (bf16 out, pitch ldc)
// MODE 1: part[z] (+)= ghid[:, klo:klo+kspan] @ W2t^T   (fp32 RMW)
#define MFMA_QUAD(MB, NB, AF, BQ)                                              \
  _Pragma("unroll") for (int mi_ = 0; mi_ < 4; ++mi_)                          \
  _Pragma("unroll") for (int ni_ = 0; ni_ < 2; ++ni_) {                        \
      acc[(MB)+mi_][(NB)+ni_] = __builtin_amdgcn_mfma_f32_16x16x32_bf16(       \
          BQ[ni_][1], AF[mi_][1], __builtin_amdgcn_mfma_f32_16x16x32_bf16(     \
          BQ[ni_][0], AF[mi_][0], acc[(MB)+mi_][(NB)+ni_], 0, 0, 0), 0, 0, 0); \
  }

#define BARX()   __builtin_amdgcn_s_barrier()
#define SBX()    __builtin_amdgcn_sched_barrier(0)
#define LGKM(N)  asm volatile("s_waitcnt lgkmcnt(" #N ")" ::: "memory")
#define VMC(N)   asm volatile("s_waitcnt vmcnt(" #N ")" ::: "memory")
#define PRIO1()  __builtin_amdgcn_s_setprio(1)
#define PRIO0()  __builtin_amdgcn_s_setprio(0)

template <int MODE>
__global__ __launch_bounds__(512) void moe_gemm8p(
    const unsigned short* __restrict__ A, int ldga,
    const unsigned short* __restrict__ Bbase, size_t estride, int ldb,
    const float* __restrict__ b1, const float* __restrict__ mw,
    unsigned short* __restrict__ Cg, int ldc,
    float* __restrict__ part,
    int logFc, int f0glob, int kspan, int init)
{
    __shared__ unsigned short sh[65536];   // 128 KiB: XA,XB,YA,YB (32KB each)
    char* sm = (char*)sh;
    const int XA = 0, XB = 32768, YA = 65536, YB = 98304;

    const int tid = threadIdx.x, lane = tid & 63, wv = tid >> 6;
    const int wr = wv >> 2, wc = wv & 3;

    // XCD-affine bijective block mapping (flat id % 8 == XCD).
    // MODE0: each XCD keeps a FIXED 4-panel A slice (2 MB, L2-resident all
    // dispatch) and its concurrent c8-group shares B panels (by sweeps
    // slowest across j) -> B working set 4 MB instead of 16.8 MB.
    int bx, by;
    if constexpr (MODE == 0) {
        const int orig = blockIdx.x + blockIdx.y * 32;  // [0, 32*gy)
        const int c8 = orig & 7, j = orig >> 3;         // j in [0, 4*gy)
        bx = c8 * 4 + (j & 3); by = j >> 2;             // by in [0, gy)
    } else {
        const int orig = blockIdx.x + blockIdx.y * 32;  // [0,128)
        const int c8 = orig & 7, j = orig >> 3;         // [0,16)
        bx = c8 * 4 + (j >> 2); by = j & 3;
    }
    const int m0 = bx * 256;
    const int n0 = by * 256;

    const int z = (MODE == 1) ? blockIdx.z : 0;
    const int klo = z * kspan;
    float* Cacc = (MODE == 1) ? part + (size_t)z * (8192 * 1024) : nullptr;

    // MODE0 fixed expert / B base
    int e0 = 0, fb = 0;
    const unsigned short* gB0 = nullptr;
    const int rl0 = tid >> 3;                          // row [0,64)
    const int gs8 = ((tid & 7) ^ (rl0 & 7)) * 8;       // XOR-swizzled src col
    if constexpr (MODE == 0) {
        e0 = n0 >> logFc; fb = n0 - (e0 << logFc);
        gB0 = Bbase + (size_t)e0 * estride + (size_t)(fb + rl0) * ldb + gs8;
    }
    const unsigned short* gA0 = A + (size_t)(m0 + rl0) * ldga + gs8;
    const int dstw = wv * 1024;

    auto stageA = [&](int reg, int kk, int q) {
        GLOAD_LDS16(gA0 + kk + (size_t)(q * 64) * ldga,
                    sm + reg + (q >> 1) * 16384 + (q & 1) * 8192 + dstw);
    };
    auto stageB = [&](int reg, int kk, int q) {
        const unsigned short* gb;
        if constexpr (MODE == 0) {
            gb = gB0 + kk;
        } else {
            const int e = kk >> logFc, kc = kk - (e << logFc);
            gb = Bbase + (size_t)e * estride + (size_t)(n0 + rl0) * ldb + kc + gs8;
        }
        GLOAD_LDS16(gb + (size_t)(q * 64) * ldb,
                    sm + reg + (q >> 1) * 16384 + (q & 1) * 8192 + dstw);
    };

    // ds_read swizzled addresses
    const int l15 = lane & 15, l4 = lane >> 4, l7 = lane & 7;
    const int sA0 = (wr * 128 + l15) * 128 + (((0 + l4) ^ l7) << 4);
    const int sA1 = (wr * 128 + l15) * 128 + (((4 + l4) ^ l7) << 4);
    const int sB0 = (wc * 64 + l15) * 128 + (((0 + l4) ^ l7) << 4);
    const int sB1 = (wc * 64 + l15) * 128 + (((4 + l4) ^ l7) << 4);

    f32x4 acc[8][4] = {};
    bf16x8 afL[4][2], afH[4][2], bqL[2][2], bqH[2][2];

#define RD_AFL(BASE) _Pragma("unroll") for (int mi_=0;mi_<4;++mi_){            \
      afL[mi_][0] = *(const bf16x8*)(sm + (BASE) + sA0 + mi_*2048);            \
      afL[mi_][1] = *(const bf16x8*)(sm + (BASE) + sA1 + mi_*2048); }
#define RD_AFH(BASE) _Pragma("unroll") for (int mi_=0;mi_<4;++mi_){            \
      afH[mi_][0] = *(const bf16x8*)(sm + (BASE) + sA0 + (4+mi_)*2048);        \
      afH[mi_][1] = *(const bf16x8*)(sm + (BASE) + sA1 + (4+mi_)*2048); }
#define RD_BQL(BASE) _Pragma("unroll") for (int ni_=0;ni_<2;++ni_){            \
      bqL[ni_][0] = *(const bf16x8*)(sm + (BASE) + sB0 + ni_*2048);            \
      bqL[ni_][1] = *(const bf16x8*)(sm + (BASE) + sB1 + ni_*2048); }
#define RD_BQH(BASE) _Pragma("unroll") for (int ni_=0;ni_<2;++ni_){            \
      bqH[ni_][0] = *(const bf16x8*)(sm + (BASE) + sB0 + (2+ni_)*2048);        \
      bqH[ni_][1] = *(const bf16x8*)(sm + (BASE) + sB1 + (2+ni_)*2048); }

    const int niter = kspan >> 7;  // 2 K-tiles (2x64) per iteration

    // Prologue: stage X(t0), Y(t1); drain X; read X Q1 frags after barrier.
#pragma unroll
    for (int q = 0; q < 4; ++q) { stageA(XA, klo, q); stageB(XB, klo, q); }
#pragma unroll
    for (int q = 0; q < 4; ++q) { stageA(YA, klo + 64, q); stageB(YB, klo + 64, q); }
    VMC(8); SBX();
    BARX();
    RD_AFL(XA); RD_BQL(XB);

    for (int it = 0; it < niter; ++it) {
        const int kX2 = klo + it * 128 + 128;  // next X tile
        const int kY2 = klo + it * 128 + 192;  // next Y tile
        const bool g = (it + 1 < niter);
        // ---- P1: MFMA Q1(X); read-ahead bqH(X)
        RD_BQH(XB);
        BARX(); LGKM(4); SBX(); PRIO1(); MFMA_QUAD(0, 0, afL, bqL); PRIO0(); BARX();
        // ---- P2: MFMA Q2(X); read-ahead afH(X); stage nextX A q0,q2
        RD_AFH(XA);
        if (g) { stageA(XA, kX2, 0); stageA(XA, kX2, 2); }
        BARX(); LGKM(8); SBX(); PRIO1(); MFMA_QUAD(0, 2, afL, bqH); PRIO0(); BARX();
        // ---- P3: MFMA Q3(X); stage nextX B q0,q1
        if (g) { stageB(XB, kX2, 0); stageB(XB, kX2, 1); }
        BARX(); LGKM(0); SBX(); PRIO1(); MFMA_QUAD(4, 0, afH, bqL); PRIO0(); BARX();
        // ---- P4: stage nextX rest; vmcnt; barrier; read Y Q1; MFMA Q4(X)
        if (g) { stageA(XA, kX2, 1); stageA(XA, kX2, 3);
                 stageB(XB, kX2, 2); stageB(XB, kX2, 3);
                 VMC(8); } else { VMC(0); }
        SBX();
        BARX();
        RD_AFL(YA); RD_BQL(YB);
        SBX(); PRIO1(); MFMA_QUAD(4, 2, afH, bqH); PRIO0(); BARX();
        // ---- P5: MFMA Q1(Y); read-ahead bqH(Y)
        RD_BQH(YB);
        BARX(); LGKM(4); SBX(); PRIO1(); MFMA_QUAD(0, 0, afL, bqL); PRIO0(); BARX();
        // ---- P6: MFMA Q2(Y); read-ahead afH(Y); stage nextY A q0,q2
        RD_AFH(YA);
        if (g) { stageA(YA, kY2, 0); stageA(YA, kY2, 2); }
        BARX(); LGKM(8); SBX(); PRIO1(); MFMA_QUAD(0, 2, afL, bqH); PRIO0(); BARX();
        // ---- P7: MFMA Q3(Y); stage nextY B q0,q1
        if (g) { stageB(YB, kY2, 0); stageB(YB, kY2, 1); }
        BARX(); LGKM(0); SBX(); PRIO1(); MFMA_QUAD(4, 0, afH, bqL); PRIO0(); BARX();
        // ---- P8: stage nextY rest; vmcnt; barrier; read nextX Q1; MFMA Q4(Y)
        if (g) { stageA(YA, kY2, 1); stageA(YA, kY2, 3);
                 stageB(YB, kY2, 2); stageB(YB, kY2, 3);
                 VMC(8); } else { VMC(0); }
        SBX();
        BARX();
        if (g) { RD_AFL(XA); RD_BQL(XB); }
        SBX(); PRIO1(); MFMA_QUAD(4, 2, afH, bqH); PRIO0(); BARX();
    }

    // Epilogue
    const int nr0v = l4 * 4;
    if constexpr (MODE == 0) {
        const float* b1p = b1 + (size_t)e0 * 4096 + f0glob + fb;
        f32x4 b1v[4];
#pragma unroll
        for (int j = 0; j < 4; ++j)
            b1v[j] = *(const f32x4*)(b1p + wc * 64 + j * 16 + nr0v);
#pragma unroll
        for (int i = 0; i < 8; ++i) {
            const int token = m0 + wr * 128 + i * 16 + l15;
            const float w = mw[(size_t)token * 8 + e0];
            unsigned short* crow = Cg + (size_t)token * ldc + n0;
#pragma unroll
            for (int j = 0; j < 4; ++j) {
                const int n = wc * 64 + j * 16 + nr0v;
                us4 o;
#pragma unroll
                for (int r = 0; r < 4; ++r)
                    o[r] = f2bf(w * gelu_fast(acc[i][j][r] + b1v[j][r]));
                *(us4*)(crow + n) = o;
            }
        }
    } else {
#pragma unroll
        for (int i = 0; i < 8; ++i) {
            const int row = m0 + wr * 128 + i * 16 + l15;
            float* cp = Cacc + (size_t)row * 1024 + n0;
#pragma unroll
            for (int j = 0; j < 4; ++j) {
                const int n = wc * 64 + j * 16 + nr0v;
                if (init) {
                    *(f32x4*)(cp + n) = acc[i][j];
                } else {
                    f32x4 old = *(const f32x4*)(cp + n);
                    *(f32x4*)(cp + n) = old + acc[i][j];
                }
            }
        }
    }
}

// ------------- Combine: out = sum_z part[z] + sum_e mw*b2 --------------------
__global__ __launch_bounds__(256) void moe_combine_kernel(
    const float* __restrict__ part, int S,
    float* __restrict__ out, const float* __restrict__ mw,
    const float* __restrict__ b2)
{
    const int n = blockIdx.x, t = threadIdx.x;
    const int d = t * 4;
    f32x4 v = *(const f32x4*)(part + (size_t)n * 1024 + d);
    for (int z = 1; z < S; ++z)
        v = v + *(const f32x4*)(part + (size_t)z * (8192 * 1024) + (size_t)n * 1024 + d);
#pragma unroll
    for (int e = 0; e < 8; ++e) {
        const float w = mw[(size_t)n * 8 + e];
        const f32x4 b = *(const f32x4*)(b2 + (size_t)e * 1024 + d);
        v = v + w * b;
    }
    *(f32x4*)(out + (size_t)n * 1024 + d) = v;
}

extern "C" void kernel_launch(void* const* d_in, const int* in_sizes, int n_in,
                              void* d_out, int out_size, void* d_ws, size_t ws_size,
                              hipStream_t stream)
{
    (void)in_sizes; (void)n_in; (void)out_size;
    const float* h  = (const float*)d_in[0];
    const float* Wr = (const float*)d_in[1];
    const float* br = (const float*)d_in[2];
    const float* W1 = (const float*)d_in[3];
    const float* b1 = (const float*)d_in[4];
    const float* W2 = (const float*)d_in[5];
    const float* b2 = (const float*)d_in[6];
    float* out = (float*)d_out;   // fp32 output [N][D]

    const int N = 8192, D = 1024, F = 4096, E = 8;
    const int S = 2;
    auto al = [](size_t x) { return (x + 255) & ~(size_t)255; };
    const size_t sz_hbf = al((size_t)N * D * 2);
    const size_t sz_mw  = al((size_t)N * E * 4);
    const size_t sz_pt1 = al((size_t)N * D * 4);
    // chunk-local weight buffers (no full-transpose path)
    auto tot = [&](int fc) {
        size_t s = sz_hbf + sz_mw + al((size_t)N * ((size_t)E * fc + 32) * 2);
        s += al((size_t)E * fc * D * 2) * 2;
        s += (size_t)S * sz_pt1;
        return s;
    };
    int Fc;
    if      (tot(1024) <= ws_size) Fc = 1024;
    else if (tot(512)  <= ws_size) Fc = 512;
    else                           Fc = 256;
    const int logFc = (Fc == 1024) ? 10 : (Fc == 512) ? 9 : 8;
    const int Kc = E * Fc;
    const int ldAp = Kc + 32;   // padded ghid pitch (breaks pow2 row alias)

    char* p = (char*)d_ws;
    unsigned short* hbf = (unsigned short*)p; p += sz_hbf;
    float* mwp  = (float*)p; p += sz_mw;
    unsigned short* ghid = (unsigned short*)p; p += al((size_t)N * (size_t)ldAp * 2);
    unsigned short* W1t  = (unsigned short*)p; p += al((size_t)E * Fc * D * 2);
    unsigned short* W2t  = (unsigned short*)p; p += al((size_t)E * Fc * D * 2);
    float* part = (float*)p;

    moe_router_kernel<<<N / 4, 256, 0, stream>>>(h, Wr, br, hbf, mwp);

    const int nch = F / Fc;
    for (int c = 0; c < nch; ++c) {
        // chunk-local transposed bf16 weights
        moe_tcvt_kernel<<<dim3(D / 32, Fc / 32, E), 256, 0, stream>>>(
            W1 + (size_t)c * Fc, W1t, F, (size_t)D * F, D, (size_t)Fc * D);
        moe_tcvt_kernel<<<dim3(Fc / 32, D / 32, E), 256, 0, stream>>>(
            W2 + (size_t)c * Fc * D, W2t, D, (size_t)F * D, Fc, (size_t)D * Fc);

        moe_gemm8p<0><<<dim3(32, Kc / 256, 1), 512, 0, stream>>>(
            hbf, 1024, W1t, (size_t)Fc * D, 1024, b1, mwp, ghid, ldAp, nullptr,
            logFc, c * Fc, /*kspan=*/1024, 0);

        moe_gemm8p<1><<<dim3(32, 4, S), 512, 0, stream>>>(
            ghid, ldAp, W2t, (size_t)D * Fc, Fc, nullptr, nullptr, nullptr, 0, part,
            logFc, 0, /*kspan=*/Kc / S, (c == 0) ? 1 : 0);
    }

    moe_combine_kernel<<<N, 256, 0, stream>>>(part, S, out, mwp, b2);
}

// Round 16
// 1238.020 us; speedup vs baseline: 1.0524x; 1.0039x over previous
//
#include <hip/hip_runtime.h>
#include <hip/hip_bf16.h>
#include <cstdint>
#include <cstddef>

typedef __attribute__((ext_vector_type(8))) __bf16 bf16x8;
typedef __attribute__((ext_vector_type(4))) float f32x4;
typedef __attribute__((ext_vector_type(4))) unsigned short us4;

#define GLOAD_LDS16(g, l)                                                        \
    __builtin_amdgcn_global_load_lds(                                            \
        (const __attribute__((address_space(1))) void*)(g),                      \
        (__attribute__((address_space(3))) void*)(l), 16, 0, 0)

static __device__ __forceinline__ unsigned short f2bf(float x) {
    unsigned int u = __builtin_bit_cast(unsigned int, x);
    return (unsigned short)((u + 0x7FFFu + ((u >> 16) & 1u)) >> 16);
}

// gelu(x) = x * sigmoid(1.5957691x + 0.0713548x^3)  (== tanh-form gelu)
static __device__ __forceinline__ float gelu_fast(float x) {
    const float p = x * x;
    const float u = x * fmaf(0.0713548162726f, p, 1.59576912161f);
    const float t = __expf(-u);
    return x * __builtin_amdgcn_rcpf(1.0f + t);
}

// ---------------- Router: logits -> softmax -> mask, plus h -> bf16 ----------
__global__ __launch_bounds__(256) void moe_router_kernel(
    const float* __restrict__ h, const float* __restrict__ Wr,
    const float* __restrict__ br, unsigned short* __restrict__ hbf,
    float* __restrict__ mw)
{
    const int lane = threadIdx.x & 63, wave = threadIdx.x >> 6;
    const int n = blockIdx.x * 4 + wave;  // one token per wave
    const float* hr = h + (size_t)n * 1024;
    const int base = lane * 16;

    float xs[16];
#pragma unroll
    for (int q = 0; q < 4; ++q) {
        f32x4 v = *(const f32x4*)(hr + base + q * 4);
        xs[q * 4 + 0] = v[0]; xs[q * 4 + 1] = v[1];
        xs[q * 4 + 2] = v[2]; xs[q * 4 + 3] = v[3];
    }
    float acc[8] = {0.f, 0.f, 0.f, 0.f, 0.f, 0.f, 0.f, 0.f};
#pragma unroll
    for (int j = 0; j < 16; ++j) {
        const float x = xs[j];
        const f32x4 w0 = *(const f32x4*)(Wr + (size_t)(base + j) * 8);
        const f32x4 w1 = *(const f32x4*)(Wr + (size_t)(base + j) * 8 + 4);
        acc[0] += x * w0[0]; acc[1] += x * w0[1]; acc[2] += x * w0[2]; acc[3] += x * w0[3];
        acc[4] += x * w1[0]; acc[5] += x * w1[1]; acc[6] += x * w1[2]; acc[7] += x * w1[3];
    }
#pragma unroll
    for (int q = 0; q < 4; ++q) {
        us4 o;
        o[0] = f2bf(xs[q * 4 + 0]); o[1] = f2bf(xs[q * 4 + 1]);
        o[2] = f2bf(xs[q * 4 + 2]); o[3] = f2bf(xs[q * 4 + 3]);
        *(us4*)(hbf + (size_t)n * 1024 + base + q * 4) = o;
    }
#pragma unroll
    for (int m = 32; m >= 1; m >>= 1)
#pragma unroll
        for (int e = 0; e < 8; ++e) acc[e] += __shfl_xor(acc[e], m, 64);

    if (lane == 0) {
        float l[8]; float mx = -1e30f;
#pragma unroll
        for (int e = 0; e < 8; ++e) { l[e] = acc[e] + br[e]; mx = fmaxf(mx, l[e]); }
        float s = 0.f;
#pragma unroll
        for (int e = 0; e < 8; ++e) { l[e] = __expf(l[e] - mx); s += l[e]; }
        const float inv = 1.0f / s;
#pragma unroll
        for (int e = 0; e < 8; ++e) {
            const float w = l[e] * inv;
            mw[(size_t)n * 8 + e] = (w > 0.05f) ? w : 0.0f;
        }
    }
}

// ---------- Transpose + fp32->bf16 convert (32x32 tiles, per expert z) -------
// Fallback path for Fc != 1024.
__global__ __launch_bounds__(256) void moe_tcvt_kernel(
    const float* __restrict__ in, unsigned short* __restrict__ out,
    int ls, size_t in_es, int os, size_t out_es)
{
    __shared__ unsigned short t[32][33];
    const int e = blockIdx.z;
    const int r = threadIdx.x >> 3, c = (threadIdx.x & 7) * 4;
    const float* I = in + (size_t)e * in_es + (size_t)(blockIdx.x * 32 + r) * ls + blockIdx.y * 32 + c;
    f32x4 v = *(const f32x4*)I;
    t[r][c + 0] = f2bf(v[0]); t[r][c + 1] = f2bf(v[1]);
    t[r][c + 2] = f2bf(v[2]); t[r][c + 3] = f2bf(v[3]);
    __syncthreads();
    unsigned short* O = out + (size_t)e * out_es + (size_t)(blockIdx.y * 32 + r) * os + blockIdx.x * 32 + c;
    us4 o;
    o[0] = t[c + 0][r]; o[1] = t[c + 1][r]; o[2] = t[c + 2][r]; o[3] = t[c + 3][r];
    *(us4*)O = o;
}

// ------ Merged 64x64 transpose-convert for Fc=1024 (W1 z<8, W2 z>=8) ---------
__global__ __launch_bounds__(256) void moe_tcvt64_kernel(
    const float* __restrict__ W1, const float* __restrict__ W2,
    unsigned short* __restrict__ W1t, unsigned short* __restrict__ W2t, int c)
{
    __shared__ unsigned short t[64][65];
    const int z = blockIdx.z;
    const float* in; unsigned short* out; int ld_in;
    if (z < 8) {
        in = W1 + (size_t)z * 1024 * 4096 + (size_t)c * 1024;  // [1024][Fc] ld 4096
        ld_in = 4096;
        out = W1t + (size_t)z * 1024 * 1024;                   // [Fc][1024] ld 1024
    } else {
        const int e = z - 8;
        in = W2 + (size_t)e * 4096 * 1024 + (size_t)c * 1024 * 1024; // [Fc][1024]
        ld_in = 1024;
        out = W2t + (size_t)e * 1024 * 1024;                   // [1024][Fc] ld 1024
    }
    const int r0 = threadIdx.x >> 4;
    const int c4 = (threadIdx.x & 15) * 4;
    const int gr = blockIdx.x * 64, gc = blockIdx.y * 64;
#pragma unroll
    for (int q = 0; q < 4; ++q) {
        const int r = r0 + q * 16;
        f32x4 v = *(const f32x4*)(in + (size_t)(gr + r) * ld_in + gc + c4);
        t[r][c4 + 0] = f2bf(v[0]); t[r][c4 + 1] = f2bf(v[1]);
        t[r][c4 + 2] = f2bf(v[2]); t[r][c4 + 3] = f2bf(v[3]);
    }
    __syncthreads();
#pragma unroll
    for (int q = 0; q < 4; ++q) {
        const int cc = r0 + q * 16;
        us4 o;
        o[0] = t[c4 + 0][cc]; o[1] = t[c4 + 1][cc];
        o[2] = t[c4 + 2][cc]; o[3] = t[c4 + 3][cc];
        *(us4*)(out + (size_t)(gc + cc) * 1024 + gr + c4) = o;
    }
}

// ============ 8-phase 256x256 GEMM, BK=64, look-ahead ds_read pipeline =======
// MODE 0 (persistent multi-tile dense): 256 blocks; block owns m-slice bx
//   (c8-affine: XCD's A slice = 2 MB L2-resident) and walks tpb n-tiles
//   (exclusive B panels) via virtual K = tpb*1024.  Per-tile epilogue every
//   8 iters, followed by vmcnt(0) ledger reset (keeps counted-vmcnt pipeline
//   sound despite epilogue stores/loads -- R9 lesson).
//   ghid = mw * gelu(hbf @ W1t^T + b1)
// MODE 1: part[z] (+)= ghid[:, klo:klo+kspan] @ W2t^T   (fp32 RMW)
#define MFMA_QUAD(MB, NB, AF, BQ)                                              \
  _Pragma("unroll") for (int mi_ = 0; mi_ < 4; ++mi_)                          \
  _Pragma("unroll") for (int ni_ = 0; ni_ < 2; ++ni_) {                        \
      acc[(MB)+mi_][(NB)+ni_] = __builtin_amdgcn_mfma_f32_16x16x32_bf16(       \
          BQ[ni_][1], AF[mi_][1], __builtin_amdgcn_mfma_f32_16x16x32_bf16(     \
          BQ[ni_][0], AF[mi_][0], acc[(MB)+mi_][(NB)+ni_], 0, 0, 0), 0, 0, 0); \
  }

#define BARX()   __builtin_amdgcn_s_barrier()
#define SBX()    __builtin_amdgcn_sched_barrier(0)
#define LGKM(N)  asm volatile("s_waitcnt lgkmcnt(" #N ")" ::: "memory")
#define VMC(N)   asm volatile("s_waitcnt vmcnt(" #N ")" ::: "memory")
#define PRIO1()  __builtin_amdgcn_s_setprio(1)
#define PRIO0()  __builtin_amdgcn_s_setprio(0)

template <int MODE>
__global__ __launch_bounds__(512) void moe_gemm8p(
    const unsigned short* __restrict__ A, int ldga,
    const unsigned short* __restrict__ Bbase, size_t estride, int ldb,
    const float* __restrict__ b1, const float* __restrict__ mw,
    unsigned short* __restrict__ Cg, int ldc,
    float* __restrict__ part,
    int logFc, int f0glob, int kspan, int init)
{
    __shared__ unsigned short sh[65536];   // 128 KiB: XA,XB,YA,YB (32KB each)
    char* sm = (char*)sh;
    const int XA = 0, XB = 32768, YA = 65536, YB = 98304;

    const int tid = threadIdx.x, lane = tid & 63, wv = tid >> 6;
    const int wr = wv >> 2, wc = wv & 3;

    // XCD-affine bijective block mapping (flat id % 8 == XCD).
    int bx, by = 0, byg = 0;
    if constexpr (MODE == 0) {
        const int orig = blockIdx.x + blockIdx.y * 32;  // [0,256)
        const int c8 = orig & 7, j = orig >> 3;         // j in [0,32)
        bx = c8 * 4 + (j & 3);                          // fixed A slice per XCD
        byg = j >> 2;                                   // [0,8): n-tile group
    } else {
        const int orig = blockIdx.x + blockIdx.y * 32;  // [0,128)
        const int c8 = orig & 7, j = orig >> 3;         // [0,16)
        bx = c8 * 4 + (j >> 2); by = j & 3;
    }
    const int m0 = bx * 256;
    const int n0 = by * 256;
    const int tpb = (MODE == 0) ? (kspan >> 10) : 0;    // n-tiles per block

    const int z = (MODE == 1) ? blockIdx.z : 0;
    const int klo = (MODE == 1) ? z * kspan : 0;
    float* Cacc = (MODE == 1) ? part + (size_t)z * (8192 * 1024) : nullptr;

    const int rl0 = tid >> 3;                          // row [0,64)
    const int gs8 = ((tid & 7) ^ (rl0 & 7)) * 8;       // XOR-swizzled src col
    const int l15 = lane & 15, l4 = lane >> 4, l7 = lane & 7;
    const int nr0v = l4 * 4;

    const unsigned short* gA0 = A + (size_t)(m0 + rl0) * ldga + gs8;
    const int dstw = wv * 1024;

    auto stageA = [&](int reg, int kv, int q) {
        const int kcol = (MODE == 0) ? (kv & 1023) : kv;
        GLOAD_LDS16(gA0 + kcol + (size_t)(q * 64) * ldga,
                    sm + reg + (q >> 1) * 16384 + (q & 1) * 8192 + dstw);
    };
    auto stageB = [&](int reg, int kv, int q) {
        const unsigned short* gb;
        if constexpr (MODE == 0) {
            const int tile = kv >> 10;
            const int n0t = (byg * tpb + tile) << 8;
            const int e = n0t >> logFc, fbt = n0t - (e << logFc);
            gb = Bbase + (size_t)e * estride + (size_t)(fbt + rl0) * ldb
               + (kv & 1023) + gs8;
        } else {
            const int e = kv >> logFc, kc = kv - (e << logFc);
            gb = Bbase + (size_t)e * estride + (size_t)(n0 + rl0) * ldb + kc + gs8;
        }
        GLOAD_LDS16(gb + (size_t)(q * 64) * ldb,
                    sm + reg + (q >> 1) * 16384 + (q & 1) * 8192 + dstw);
    };

    // ds_read swizzled addresses
    const int sA0 = (wr * 128 + l15) * 128 + (((0 + l4) ^ l7) << 4);
    const int sA1 = (wr * 128 + l15) * 128 + (((4 + l4) ^ l7) << 4);
    const int sB0 = (wc * 64 + l15) * 128 + (((0 + l4) ^ l7) << 4);
    const int sB1 = (wc * 64 + l15) * 128 + (((4 + l4) ^ l7) << 4);

    f32x4 acc[8][4] = {};
    bf16x8 afL[4][2], afH[4][2], bqL[2][2], bqH[2][2];

#define RD_AFL(BASE) _Pragma("unroll") for (int mi_=0;mi_<4;++mi_){            \
      afL[mi_][0] = *(const bf16x8*)(sm + (BASE) + sA0 + mi_*2048);            \
      afL[mi_][1] = *(const bf16x8*)(sm + (BASE) + sA1 + mi_*2048); }
#define RD_AFH(BASE) _Pragma("unroll") for (int mi_=0;mi_<4;++mi_){            \
      afH[mi_][0] = *(const bf16x8*)(sm + (BASE) + sA0 + (4+mi_)*2048);        \
      afH[mi_][1] = *(const bf16x8*)(sm + (BASE) + sA1 + (4+mi_)*2048); }
#define RD_BQL(BASE) _Pragma("unroll") for (int ni_=0;ni_<2;++ni_){            \
      bqL[ni_][0] = *(const bf16x8*)(sm + (BASE) + sB0 + ni_*2048);            \
      bqL[ni_][1] = *(const bf16x8*)(sm + (BASE) + sB1 + ni_*2048); }
#define RD_BQH(BASE) _Pragma("unroll") for (int ni_=0;ni_<2;++ni_){            \
      bqH[ni_][0] = *(const bf16x8*)(sm + (BASE) + sB0 + (2+ni_)*2048);        \
      bqH[ni_][1] = *(const bf16x8*)(sm + (BASE) + sB1 + (2+ni_)*2048); }

    const int niter = kspan >> 7;  // 2 K-tiles (2x64) per iteration

    // Prologue: stage X(t0), Y(t1); drain X; read X Q1 frags after barrier.
#pragma unroll
    for (int q = 0; q < 4; ++q) { stageA(XA, klo, q); stageB(XB, klo, q); }
#pragma unroll
    for (int q = 0; q < 4; ++q) { stageA(YA, klo + 64, q); stageB(YB, klo + 64, q); }
    VMC(8); SBX();
    BARX();
    RD_AFL(XA); RD_BQL(XB);

    for (int it = 0; it < niter; ++it) {
        const int kX2 = klo + it * 128 + 128;  // next X tile
        const int kY2 = klo + it * 128 + 192;  // next Y tile
        const bool g = (it + 1 < niter);
        // ---- P1: MFMA Q1(X); read-ahead bqH(X)
        RD_BQH(XB);
        BARX(); LGKM(4); SBX(); PRIO1(); MFMA_QUAD(0, 0, afL, bqL); PRIO0(); BARX();
        // ---- P2: MFMA Q2(X); read-ahead afH(X); stage nextX A q0,q2
        RD_AFH(XA);
        if (g) { stageA(XA, kX2, 0); stageA(XA, kX2, 2); }
        BARX(); LGKM(8); SBX(); PRIO1(); MFMA_QUAD(0, 2, afL, bqH); PRIO0(); BARX();
        // ---- P3: MFMA Q3(X); stage nextX B q0,q1
        if (g) { stageB(XB, kX2, 0); stageB(XB, kX2, 1); }
        BARX(); LGKM(0); SBX(); PRIO1(); MFMA_QUAD(4, 0, afH, bqL); PRIO0(); BARX();
        // ---- P4: stage nextX rest; vmcnt; barrier; read Y Q1; MFMA Q4(X)
        if (g) { stageA(XA, kX2, 1); stageA(XA, kX2, 3);
                 stageB(XB, kX2, 2); stageB(XB, kX2, 3);
                 VMC(8); } else { VMC(0); }
        SBX();
        BARX();
        RD_AFL(YA); RD_BQL(YB);
        SBX(); PRIO1(); MFMA_QUAD(4, 2, afH, bqH); PRIO0(); BARX();
        // ---- P5: MFMA Q1(Y); read-ahead bqH(Y)
        RD_BQH(YB);
        BARX(); LGKM(4); SBX(); PRIO1(); MFMA_QUAD(0, 0, afL, bqL); PRIO0(); BARX();
        // ---- P6: MFMA Q2(Y); read-ahead afH(Y); stage nextY A q0,q2
        RD_AFH(YA);
        if (g) { stageA(YA, kY2, 0); stageA(YA, kY2, 2); }
        BARX(); LGKM(8); SBX(); PRIO1(); MFMA_QUAD(0, 2, afL, bqH); PRIO0(); BARX();
        // ---- P7: MFMA Q3(Y); stage nextY B q0,q1
        if (g) { stageB(YB, kY2, 0); stageB(YB, kY2, 1); }
        BARX(); LGKM(0); SBX(); PRIO1(); MFMA_QUAD(4, 0, afH, bqL); PRIO0(); BARX();
        // ---- P8: stage nextY rest; vmcnt; barrier; read nextX Q1; MFMA Q4(Y)
        if (g) { stageA(YA, kY2, 1); stageA(YA, kY2, 3);
                 stageB(YB, kY2, 2); stageB(YB, kY2, 3);
                 VMC(8); } else { VMC(0); }
        SBX();
        BARX();
        if (g) { RD_AFL(XA); RD_BQL(XB); }
        SBX(); PRIO1(); MFMA_QUAD(4, 2, afH, bqH); PRIO0(); BARX();

        // MODE0: per-tile epilogue every 8 iters (one K=1024 n-tile done).
        if constexpr (MODE == 0) {
            if ((it & 7) == 7) {
                const int tile = it >> 3;
                const int n0t = (byg * tpb + tile) << 8;
                const int e0t = n0t >> logFc, fbt = n0t - (e0t << logFc);
                const float* b1p = b1 + (size_t)e0t * 4096 + f0glob + fbt;
                f32x4 b1v[4];
#pragma unroll
                for (int j = 0; j < 4; ++j)
                    b1v[j] = *(const f32x4*)(b1p + wc * 64 + j * 16 + nr0v);
#pragma unroll
                for (int i = 0; i < 8; ++i) {
                    const int token = m0 + wr * 128 + i * 16 + l15;
                    const float w = mw[(size_t)token * 8 + e0t];
                    unsigned short* crow = Cg + (size_t)token * ldc + n0t;
#pragma unroll
                    for (int j = 0; j < 4; ++j) {
                        const int n = wc * 64 + j * 16 + nr0v;
                        us4 o;
#pragma unroll
                        for (int r = 0; r < 4; ++r)
                            o[r] = f2bf(w * gelu_fast(acc[i][j][r] + b1v[j][r]));
                        *(us4*)(crow + n) = o;
                        acc[i][j] = (f32x4){0.f, 0.f, 0.f, 0.f};
                    }
                }
                // Ledger reset: epilogue stores/loads leave vmcnt unknown;
                // drain to 0 so the next P4's VMC(8) counts only prefetches.
                VMC(0); SBX();
            }
        }
    }

    // MODE1 epilogue: vector f32x4 accumulate into part[z]
    if constexpr (MODE == 1) {
#pragma unroll
        for (int i = 0; i < 8; ++i) {
            const int row = m0 + wr * 128 + i * 16 + l15;
            float* cp = Cacc + (size_t)row * 1024 + n0;
#pragma unroll
            for (int j = 0; j < 4; ++j) {
                const int n = wc * 64 + j * 16 + nr0v;
                if (init) {
                    *(f32x4*)(cp + n) = acc[i][j];
                } else {
                    f32x4 old = *(const f32x4*)(cp + n);
                    *(f32x4*)(cp + n) = old + acc[i][j];
                }
            }
        }
    }
}

// ------------- Combine: out = sum_z part[z] + sum_e mw*b2 --------------------
__global__ __launch_bounds__(256) void moe_combine_kernel(
    const float* __restrict__ part, int S,
    float* __restrict__ out, const float* __restrict__ mw,
    const float* __restrict__ b2)
{
    const int n = blockIdx.x, t = threadIdx.x;
    const int d = t * 4;
    f32x4 v = *(const f32x4*)(part + (size_t)n * 1024 + d);
    for (int z = 1; z < S; ++z)
        v = v + *(const f32x4*)(part + (size_t)z * (8192 * 1024) + (size_t)n * 1024 + d);
#pragma unroll
    for (int e = 0; e < 8; ++e) {
        const float w = mw[(size_t)n * 8 + e];
        const f32x4 b = *(const f32x4*)(b2 + (size_t)e * 1024 + d);
        v = v + w * b;
    }
    *(f32x4*)(out + (size_t)n * 1024 + d) = v;
}

extern "C" void kernel_launch(void* const* d_in, const int* in_sizes, int n_in,
                              void* d_out, int out_size, void* d_ws, size_t ws_size,
                              hipStream_t stream)
{
    (void)in_sizes; (void)n_in; (void)out_size;
    const float* h  = (const float*)d_in[0];
    const float* Wr = (const float*)d_in[1];
    const float* br = (const float*)d_in[2];
    const float* W1 = (const float*)d_in[3];
    const float* b1 = (const float*)d_in[4];
    const float* W2 = (const float*)d_in[5];
    const float* b2 = (const float*)d_in[6];
    float* out = (float*)d_out;   // fp32 output [N][D]

    const int N = 8192, D = 1024, F = 4096, E = 8;
    const int S = 2;
    auto al = [](size_t x) { return (x + 255) & ~(size_t)255; };
    const size_t sz_hbf = al((size_t)N * D * 2);
    const size_t sz_mw  = al((size_t)N * E * 4);
    const size_t sz_pt1 = al((size_t)N * D * 4);
    // chunk-local weight buffers (no full-transpose path)
    auto tot = [&](int fc) {
        size_t s = sz_hbf + sz_mw + al((size_t)N * ((size_t)E * fc + 32) * 2);
        s += al((size_t)E * fc * D * 2) * 2;
        s += (size_t)S * sz_pt1;
        return s;
    };
    int Fc;
    if      (tot(1024) <= ws_size) Fc = 1024;
    else if (tot(512)  <= ws_size) Fc = 512;
    else                           Fc = 256;
    const int logFc = (Fc == 1024) ? 10 : (Fc == 512) ? 9 : 8;
    const int Kc = E * Fc;
    const int ldAp = Kc + 32;   // padded ghid pitch (breaks pow2 row alias)

    char* p = (char*)d_ws;
    unsigned short* hbf = (unsigned short*)p; p += sz_hbf;
    float* mwp  = (float*)p; p += sz_mw;
    unsigned short* ghid = (unsigned short*)p; p += al((size_t)N * (size_t)ldAp * 2);
    unsigned short* W1t  = (unsigned short*)p; p += al((size_t)E * Fc * D * 2);
    unsigned short* W2t  = (unsigned short*)p; p += al((size_t)E * Fc * D * 2);
    float* part = (float*)p;

    moe_router_kernel<<<N / 4, 256, 0, stream>>>(h, Wr, br, hbf, mwp);

    const int nch = F / Fc;
    for (int c = 0; c < nch; ++c) {
        if (Fc == 1024) {
            moe_tcvt64_kernel<<<dim3(16, 16, 16), 256, 0, stream>>>(
                W1, W2, W1t, W2t, c);
        } else {
            moe_tcvt_kernel<<<dim3(D / 32, Fc / 32, E), 256, 0, stream>>>(
                W1 + (size_t)c * Fc, W1t, F, (size_t)D * F, D, (size_t)Fc * D);
            moe_tcvt_kernel<<<dim3(Fc / 32, D / 32, E), 256, 0, stream>>>(
                W2 + (size_t)c * Fc * D, W2t, D, (size_t)F * D, Fc, (size_t)D * Fc);
        }

        // persistent MODE0: 256 blocks, each walks Kc/2048 n-tiles
        moe_gemm8p<0><<<dim3(32, 8, 1), 512, 0, stream>>>(
            hbf, 1024, W1t, (size_t)Fc * D, 1024, b1, mwp, ghid, ldAp, nullptr,
            logFc, c * Fc, /*kspan=*/Kc / 2, 0);

        moe_gemm8p<1><<<dim3(32, 4, S), 512, 0, stream>>>(
            ghid, ldAp, W2t, (size_t)D * Fc, Fc, nullptr, nullptr, nullptr, 0, part,
            logFc, 0, /*kspan=*/Kc / S, (c == 0) ? 1 : 0);
    }

    moe_combine_kernel<<<N, 256, 0, stream>>>(part, S, out, mwp, b2);
}